// Round 1
// baseline (285.038 us; speedup 1.0000x reference)
//
#include <hip/hip_runtime.h>
#include <hip/hip_bf16.h>

// Mean-shift: 3 iterations of X <- eta * X @ (K/deg) + (1-eta) * X,
// K = exp(2 * X^T X), D=32, N=9216. Fused attention-style formulation:
// per query i: num = sum_j x_j * w_ji, den = sum_j w_ji, w = exp(2 x_j.x_i).
// No softmax-max needed (dots bounded). MFMA 16x16x32 bf16 for both GEMMs.

#define DIM 32
#define RESO 96
#define NPT (RESO * RESO)          // 9216
#define NITER 3
#define ETA 0.5f

#define KSPLIT 4
#define KEYS_PER_WAVE (NPT / KSPLIT)   // 2304
#define CHUNK 64
#define NCHUNK (KEYS_PER_WAVE / CHUNK) // 36
#define PSTRIDE 72                     // 144 B rows: 16B-aligned for ds_read_b128

typedef __bf16 bf16_t;
typedef __bf16 v8bf __attribute__((ext_vector_type(8)));
typedef float  v4f  __attribute__((ext_vector_type(4)));

// Pack current fp32 X (DIM x NPT, d-major) into bf16 row-major (NPT x DIM)
// and bf16 col-major (DIM x NPT). Row copy gets queries*2 folded in the
// attention kernel instead (exact power-of-2, no extra quantization).
// Optionally copies X into d_out slice 0 (iteration 0 only).
__global__ void pack_kernel(const float* __restrict__ X,
                            bf16_t* __restrict__ rows,
                            bf16_t* __restrict__ cols,
                            float* __restrict__ out_copy) {
    int idx = blockIdx.x * 256 + threadIdx.x;
    if (idx >= DIM * NPT) return;
    int d = idx / NPT;
    int n = idx - d * NPT;
    float v = X[idx];
    cols[idx] = (bf16_t)v;
    rows[n * DIM + d] = (bf16_t)v;
    if (out_copy) out_copy[idx] = v;
}

// Fused mean-shift step. Block = 256 threads = 4 waves. Each block owns 16
// queries (one 16-row MFMA strip); the 4 waves split the NPT keys 4 ways and
// partial num/den are reduced through LDS at the end.
__global__ __launch_bounds__(256, 2)
void msattn_kernel(const float* __restrict__ Xcur,
                   const bf16_t* __restrict__ rows,
                   const bf16_t* __restrict__ cols,
                   float* __restrict__ Xnext) {
    // P round-trip buffer: C-layout exp(S) -> A-operand layout, per-wave region
    __shared__ __align__(16) bf16_t p_lds[4][16][PSTRIDE];
    __shared__ float rn[4][16][33];  // +1 pad: quads hit distinct banks
    __shared__ float rd[4][16];

    const int tid  = threadIdx.x;
    const int w    = tid >> 6;
    const int lane = tid & 63;
    const int quad = lane >> 4;
    const int l16  = lane & 15;
    const int q0   = blockIdx.x * 16;

    // A-frag (GEMM1): A[m=lane&15][k=quad*8+j], m=query, k=dim.
    // Fold the BW=2.0 scale into A (exact in bf16).
    v8bf afrag;
#pragma unroll
    for (int j = 0; j < 8; ++j) {
        int d = quad * 8 + j;
        float v = Xcur[d * NPT + q0 + l16];
        afrag[j] = (bf16_t)(v * 2.0f);
    }

    v4f acc0 = {0.f, 0.f, 0.f, 0.f};   // O tile, dims 0..15
    v4f acc1 = {0.f, 0.f, 0.f, 0.f};   // O tile, dims 16..31
    float den[4] = {0.f, 0.f, 0.f, 0.f};

    const int kbase = w * KEYS_PER_WAVE;
    for (int c = 0; c < NCHUNK; ++c) {
        const int kc = kbase + c * CHUNK;

        // --- GEMM1: S[q][k] = 2 * q . k  (4 key sub-tiles of 16) ---
        v4f s[4];
#pragma unroll
        for (int t = 0; t < 4; ++t) {
            // B[k=quad*8+j][n=lane&15]: key point (kc+t*16+l16), dims quad*8..+8
            const v8bf* bp = (const v8bf*)(rows + (size_t)(kc + t * 16 + l16) * DIM + quad * 8);
            s[t] = __builtin_amdgcn_mfma_f32_16x16x32_bf16(afrag, *bp,
                                                           (v4f){0.f, 0.f, 0.f, 0.f}, 0, 0, 0);
        }

        // --- exp, den accumulate, stage P into LDS (A-operand layout) ---
        // C-layout: value (t,r) is (query=quad*4+r, key=t*16+l16)
#pragma unroll
        for (int t = 0; t < 4; ++t) {
#pragma unroll
            for (int r = 0; r < 4; ++r) {
                float wv = __expf(s[t][r]);
                den[r] += wv;
                p_lds[w][quad * 4 + r][t * 16 + l16] = (bf16_t)wv;
            }
        }
        __syncthreads();

        // --- GEMM2: O[q][d] += P[q][k] * V[k][d], two K=32 steps ---
        // A2[m=lane&15][k=quad*8+j]: contiguous b128 from p_lds
        v8bf a2_0 = *(const v8bf*)&p_lds[w][l16][quad * 8];
        v8bf a2_1 = *(const v8bf*)&p_lds[w][l16][32 + quad * 8];
        // B2[k=quad*8+j][n=lane&15]: V[key][dim] = cols[dim*NPT + key], contiguous in key
        {
            const v8bf* b00 = (const v8bf*)(cols + (size_t)(l16) * NPT + kc + quad * 8);
            const v8bf* b01 = (const v8bf*)(cols + (size_t)(16 + l16) * NPT + kc + quad * 8);
            acc0 = __builtin_amdgcn_mfma_f32_16x16x32_bf16(a2_0, *b00, acc0, 0, 0, 0);
            acc1 = __builtin_amdgcn_mfma_f32_16x16x32_bf16(a2_0, *b01, acc1, 0, 0, 0);
            const v8bf* b10 = (const v8bf*)(cols + (size_t)(l16) * NPT + kc + 32 + quad * 8);
            const v8bf* b11 = (const v8bf*)(cols + (size_t)(16 + l16) * NPT + kc + 32 + quad * 8);
            acc0 = __builtin_amdgcn_mfma_f32_16x16x32_bf16(a2_1, *b10, acc0, 0, 0, 0);
            acc1 = __builtin_amdgcn_mfma_f32_16x16x32_bf16(a2_1, *b11, acc1, 0, 0, 0);
        }
        __syncthreads();   // before next chunk overwrites p_lds
    }

    // --- cross-wave reduction ---
    // O partials: (q=quad*4+r, d=n*16+l16)
#pragma unroll
    for (int r = 0; r < 4; ++r) {
        rn[w][quad * 4 + r][l16]      = acc0[r];
        rn[w][quad * 4 + r][16 + l16] = acc1[r];
    }
    // den: reduce across the 16 lanes of each quad (xor stays within quad)
#pragma unroll
    for (int m = 1; m < 16; m <<= 1) {
#pragma unroll
        for (int r = 0; r < 4; ++r) den[r] += __shfl_xor(den[r], m);
    }
    if (l16 == 0) {
#pragma unroll
        for (int r = 0; r < 4; ++r) rd[w][quad * 4 + r] = den[r];
    }
    __syncthreads();

    // --- epilogue: 512 outputs, 2 per thread ---
    {
        int q  = tid >> 4;
        int dd = tid & 15;
        float numA = rn[0][q][dd] + rn[1][q][dd] + rn[2][q][dd] + rn[3][q][dd];
        float numB = rn[0][q][dd + 16] + rn[1][q][dd + 16] + rn[2][q][dd + 16] + rn[3][q][dd + 16];
        float dn   = rd[0][q] + rd[1][q] + rd[2][q] + rd[3][q];
        float inv  = 1.0f / dn;
        int gq = q0 + q;
        float xo0 = Xcur[dd * NPT + gq];
        float xo1 = Xcur[(dd + 16) * NPT + gq];
        Xnext[dd * NPT + gq]        = ETA * numA * inv + (1.0f - ETA) * xo0;
        Xnext[(dd + 16) * NPT + gq] = ETA * numB * inv + (1.0f - ETA) * xo1;
    }
}

extern "C" void kernel_launch(void* const* d_in, const int* in_sizes, int n_in,
                              void* d_out, int out_size, void* d_ws, size_t ws_size,
                              hipStream_t stream) {
    const float* x_in = (const float*)d_in[0];
    float* out = (float*)d_out;

    bf16_t* rows = (bf16_t*)d_ws;                    // NPT x DIM bf16 (~576 KB)
    bf16_t* cols = rows + (size_t)NPT * DIM;         // DIM x NPT bf16 (~576 KB)

    const size_t DN = (size_t)DIM * NPT;
    const int pack_blocks = (DIM * NPT + 255) / 256; // 1152

    for (int it = 0; it < NITER; ++it) {
        const float* Xcur = (it == 0) ? x_in : out + (size_t)it * DN;
        float* copy_target = (it == 0) ? out : nullptr;
        pack_kernel<<<pack_blocks, 256, 0, stream>>>(Xcur, rows, cols, copy_target);
        msattn_kernel<<<NPT / 16, 256, 0, stream>>>(Xcur, rows, cols,
                                                    out + (size_t)(it + 1) * DN);
    }
}

// Round 2
// 283.167 us; speedup vs baseline: 1.0066x; 1.0066x over previous
//
#include <hip/hip_runtime.h>
#include <hip/hip_bf16.h>

// Mean-shift: 3 iterations of X <- eta * X @ (K/deg) + (1-eta) * X,
// K = exp(2 * X^T X), D=32, N=9216. Fused attention-style formulation.
// R2: no inner barriers (per-wave LDS slabs; same-wave DS ops are in-order),
// 8 waves/block, exp2-domain fold (2*log2e into A-frag), epilogue re-packs
// bf16 rows/cols for the next iteration (single pack kernel at start).

#define DIM 32
#define RESO 96
#define NPT (RESO * RESO)          // 9216
#define NITER 3
#define ETA 0.5f
#define SCALE 2.88539008f          // BW * log2(e) = 2 * 1.4426950408

#define NWAVE 8
#define KEYS_PER_WAVE (NPT / NWAVE)    // 1152
#define CHUNK 64
#define NCHUNK (KEYS_PER_WAVE / CHUNK) // 18
#define PSTRIDE 72                     // 144 B rows: 16B-aligned ds_read_b128
#define SLAB_BYTES 2432                // per-wave slab: P(2304) unioned w/ rn(2112)+rd(64)

typedef __bf16 bf16_t;
typedef __bf16 v8bf __attribute__((ext_vector_type(8)));
typedef float  v4f  __attribute__((ext_vector_type(4)));

// One-time pack of fp32 X (DIM x NPT) into bf16 row-major (NPT x DIM) and
// bf16 col-major (DIM x NPT); also copies X into d_out slice 0.
__global__ void pack_kernel(const float* __restrict__ X,
                            bf16_t* __restrict__ rows,
                            bf16_t* __restrict__ cols,
                            float* __restrict__ out_copy) {
    int idx = blockIdx.x * 256 + threadIdx.x;
    if (idx >= DIM * NPT) return;
    int d = idx / NPT;
    int n = idx - d * NPT;
    float v = X[idx];
    cols[idx] = (bf16_t)v;
    rows[n * DIM + d] = (bf16_t)v;
    out_copy[idx] = v;
}

// Fused mean-shift step. Block = 512 threads = 8 waves, 16 queries/block.
// Waves split the 9216 keys 8 ways; no inner barriers (per-wave LDS slabs).
// Epilogue also writes next iteration's bf16 rows/cols.
__global__ __launch_bounds__(512, 4)
void msattn_kernel(const float* __restrict__ Xcur,
                   const bf16_t* __restrict__ rows,
                   const bf16_t* __restrict__ cols,
                   float* __restrict__ Xnext,
                   bf16_t* __restrict__ rows_out,
                   bf16_t* __restrict__ cols_out) {
    // Per-wave slab: during K-loop holds P (16 x PSTRIDE bf16 = 2304 B);
    // after the loop, reused for num partials (16x33 f32 = 2112 B) and
    // den partials (16 f32 = 64 B at offset 2112). Same-wave reuse only.
    __shared__ __align__(16) unsigned char slab[NWAVE][SLAB_BYTES];

    const int tid  = threadIdx.x;
    const int w    = tid >> 6;
    const int lane = tid & 63;
    const int quad = lane >> 4;
    const int l16  = lane & 15;
    const int q0   = blockIdx.x * 16;

    bf16_t* p_lds = (bf16_t*)slab[w];

    // A-frag (GEMM1): A[m=lane&15][k=quad*8+j], m=query, k=dim.
    // Fold BW*log2e so weights come straight from v_exp_f32 (exp2).
    v8bf afrag;
#pragma unroll
    for (int j = 0; j < 8; ++j) {
        int d = quad * 8 + j;
        float v = Xcur[d * NPT + q0 + l16];
        afrag[j] = (bf16_t)(v * SCALE);
    }

    v4f acc0 = {0.f, 0.f, 0.f, 0.f};   // O tile, dims 0..15
    v4f acc1 = {0.f, 0.f, 0.f, 0.f};   // O tile, dims 16..31
    float den[4] = {0.f, 0.f, 0.f, 0.f};

    const int kbase = w * KEYS_PER_WAVE;
    for (int c = 0; c < NCHUNK; ++c) {
        const int kc = kbase + c * CHUNK;

        // --- GEMM1: S[q][k] = scale * q.k  (4 key sub-tiles of 16) ---
        v4f s[4];
#pragma unroll
        for (int t = 0; t < 4; ++t) {
            const v8bf* bp = (const v8bf*)(rows + (size_t)(kc + t * 16 + l16) * DIM + quad * 8);
            s[t] = __builtin_amdgcn_mfma_f32_16x16x32_bf16(afrag, *bp,
                                                           (v4f){0.f, 0.f, 0.f, 0.f}, 0, 0, 0);
        }

        // --- exp2, den accumulate, stage P in A-operand layout ---
        // C-layout: value (t,r) is (query=quad*4+r, key=t*16+l16)
#pragma unroll
        for (int t = 0; t < 4; ++t) {
#pragma unroll
            for (int r = 0; r < 4; ++r) {
                float wv = __builtin_amdgcn_exp2f(s[t][r]);
                den[r] += wv;
                p_lds[(quad * 4 + r) * PSTRIDE + t * 16 + l16] = (bf16_t)wv;
            }
        }
        // No barrier: slab is per-wave; same-wave DS ops are in-order.

        // --- GEMM2: O[q][d] += P[q][k] * V[k][d], two K=32 steps ---
        v8bf a2_0 = *(const v8bf*)&p_lds[l16 * PSTRIDE + quad * 8];
        v8bf a2_1 = *(const v8bf*)&p_lds[l16 * PSTRIDE + 32 + quad * 8];
        {
            const v8bf* b00 = (const v8bf*)(cols + (size_t)(l16) * NPT + kc + quad * 8);
            const v8bf* b01 = (const v8bf*)(cols + (size_t)(16 + l16) * NPT + kc + quad * 8);
            acc0 = __builtin_amdgcn_mfma_f32_16x16x32_bf16(a2_0, *b00, acc0, 0, 0, 0);
            acc1 = __builtin_amdgcn_mfma_f32_16x16x32_bf16(a2_0, *b01, acc1, 0, 0, 0);
            const v8bf* b10 = (const v8bf*)(cols + (size_t)(l16) * NPT + kc + 32 + quad * 8);
            const v8bf* b11 = (const v8bf*)(cols + (size_t)(16 + l16) * NPT + kc + 32 + quad * 8);
            acc0 = __builtin_amdgcn_mfma_f32_16x16x32_bf16(a2_1, *b10, acc0, 0, 0, 0);
            acc1 = __builtin_amdgcn_mfma_f32_16x16x32_bf16(a2_1, *b11, acc1, 0, 0, 0);
        }
    }

    // --- per-wave partials into own slab (reuse of P region; same wave) ---
    float* rnw = (float*)slab[w];
    float* rdw = (float*)(slab[w] + 2112);
    // den: reduce across the 16 lanes of each quad (xor stays within quad)
#pragma unroll
    for (int m = 1; m < 16; m <<= 1) {
#pragma unroll
        for (int r = 0; r < 4; ++r) den[r] += __shfl_xor(den[r], m);
    }
#pragma unroll
    for (int r = 0; r < 4; ++r) {
        rnw[(quad * 4 + r) * 33 + l16]      = acc0[r];
        rnw[(quad * 4 + r) * 33 + 16 + l16] = acc1[r];
    }
    if (l16 == 0) {
#pragma unroll
        for (int r = 0; r < 4; ++r) rdw[quad * 4 + r] = den[r];
    }
    __syncthreads();

    // --- epilogue: 512 outputs, 1 per thread; also re-pack for next iter ---
    {
        int q  = tid >> 5;
        int d  = tid & 31;
        float num = 0.f, dn = 0.f;
#pragma unroll
        for (int ww = 0; ww < NWAVE; ++ww) {
            num += ((const float*)slab[ww])[q * 33 + d];
            dn  += ((const float*)(slab[ww] + 2112))[q];
        }
        int gq = q0 + q;
        float xo = Xcur[d * NPT + gq];
        float xn = ETA * num / dn + (1.0f - ETA) * xo;
        Xnext[d * NPT + gq] = xn;
        rows_out[(size_t)gq * DIM + d] = (bf16_t)xn;
        cols_out[(size_t)d * NPT + gq] = (bf16_t)xn;
    }
}

extern "C" void kernel_launch(void* const* d_in, const int* in_sizes, int n_in,
                              void* d_out, int out_size, void* d_ws, size_t ws_size,
                              hipStream_t stream) {
    const float* x_in = (const float*)d_in[0];
    float* out = (float*)d_out;

    // Double-buffered bf16 packs (attn i reads buf[i&1], writes buf[(i+1)&1]).
    const size_t DN = (size_t)DIM * NPT;
    bf16_t* rows0 = (bf16_t*)d_ws;
    bf16_t* cols0 = rows0 + DN;
    bf16_t* rows1 = cols0 + DN;
    bf16_t* cols1 = rows1 + DN;

    const int pack_blocks = (DIM * NPT + 255) / 256; // 1152
    pack_kernel<<<pack_blocks, 256, 0, stream>>>(x_in, rows0, cols0, out);

    for (int it = 0; it < NITER; ++it) {
        const float* Xcur = (it == 0) ? x_in : out + (size_t)it * DN;
        bf16_t* rin  = (it & 1) ? rows1 : rows0;
        bf16_t* cin  = (it & 1) ? cols1 : cols0;
        bf16_t* rout = (it & 1) ? rows0 : rows1;
        bf16_t* cout = (it & 1) ? cols0 : cols1;
        msattn_kernel<<<NPT / 16, 512, 0, stream>>>(Xcur, rin, cin,
                                                    out + (size_t)(it + 1) * DN,
                                                    rout, cout);
    }
}

// Round 3
// 282.168 us; speedup vs baseline: 1.0102x; 1.0035x over previous
//
#include <hip/hip_runtime.h>
#include <hip/hip_bf16.h>

// Mean-shift: 3 iterations of X <- eta * X @ (K/deg) + (1-eta) * X,
// K = exp(2 * X^T X), D=32, N=9216. Fused attention-style formulation.
// R3: explicit register double-buffer prefetch of all 8 B-operand b128 loads
// (R2's VGPR=32 allocation serialized them -> latency-bound at ~1 load in
// flight). Everything else structurally as R2.

#define DIM 32
#define RESO 96
#define NPT (RESO * RESO)          // 9216
#define NITER 3
#define ETA 0.5f
#define SCALE 2.88539008f          // BW * log2(e) = 2 * 1.4426950408

#define NWAVE 8
#define KEYS_PER_WAVE (NPT / NWAVE)    // 1152
#define CHUNK 64
#define NCHUNK (KEYS_PER_WAVE / CHUNK) // 18
#define PSTRIDE 72                     // 144 B rows: 16B-aligned ds_read_b128
#define SLAB_BYTES 2432                // per-wave slab: P(2304) unioned w/ rn(2112)+rd(64)

typedef __bf16 bf16_t;
typedef __bf16 v8bf __attribute__((ext_vector_type(8)));
typedef float  v4f  __attribute__((ext_vector_type(4)));

// One-time pack of fp32 X (DIM x NPT) into bf16 row-major (NPT x DIM) and
// bf16 col-major (DIM x NPT); also copies X into d_out slice 0.
__global__ void pack_kernel(const float* __restrict__ X,
                            bf16_t* __restrict__ rows,
                            bf16_t* __restrict__ cols,
                            float* __restrict__ out_copy) {
    int idx = blockIdx.x * 256 + threadIdx.x;
    if (idx >= DIM * NPT) return;
    int d = idx / NPT;
    int n = idx - d * NPT;
    float v = X[idx];
    cols[idx] = (bf16_t)v;
    rows[n * DIM + d] = (bf16_t)v;
    out_copy[idx] = v;
}

__device__ __forceinline__ void load_chunk(const bf16_t* __restrict__ rows,
                                           const bf16_t* __restrict__ cols,
                                           int kc, int l16, int quad,
                                           v8bf* __restrict__ b) {
    // GEMM1 B-frags: key (kc + t*16 + l16), dims quad*8..+7 (coalesced 1KB/instr)
#pragma unroll
    for (int t = 0; t < 4; ++t)
        b[t] = *(const v8bf*)(rows + (size_t)(kc + t * 16 + l16) * DIM + quad * 8);
    // GEMM2 B-frags: V[key][dim] = cols[dim*NPT + key]
    b[4] = *(const v8bf*)(cols + (size_t)(l16) * NPT + kc + quad * 8);
    b[5] = *(const v8bf*)(cols + (size_t)(16 + l16) * NPT + kc + quad * 8);
    b[6] = *(const v8bf*)(cols + (size_t)(l16) * NPT + kc + 32 + quad * 8);
    b[7] = *(const v8bf*)(cols + (size_t)(16 + l16) * NPT + kc + 32 + quad * 8);
}

// Fused mean-shift step. Block = 512 threads = 8 waves, 16 queries/block.
// Waves split the 9216 keys 8 ways; no inner barriers (per-wave LDS slabs).
// B operands register-double-buffered: chunk c+1's 8 loads issue before
// chunk c's compute consumes the current set.
__global__ __launch_bounds__(512, 4)
void msattn_kernel(const float* __restrict__ Xcur,
                   const bf16_t* __restrict__ rows,
                   const bf16_t* __restrict__ cols,
                   float* __restrict__ Xnext,
                   bf16_t* __restrict__ rows_out,
                   bf16_t* __restrict__ cols_out) {
    __shared__ __align__(16) unsigned char slab[NWAVE][SLAB_BYTES];

    const int tid  = threadIdx.x;
    const int w    = tid >> 6;
    const int lane = tid & 63;
    const int quad = lane >> 4;
    const int l16  = lane & 15;
    const int q0   = blockIdx.x * 16;

    bf16_t* p_lds = (bf16_t*)slab[w];

    // A-frag (GEMM1): A[m=lane&15][k=quad*8+j], m=query, k=dim.
    // Fold BW*log2e so weights come straight from v_exp_f32 (exp2).
    v8bf afrag;
#pragma unroll
    for (int j = 0; j < 8; ++j) {
        int d = quad * 8 + j;
        float v = Xcur[d * NPT + q0 + l16];
        afrag[j] = (bf16_t)(v * SCALE);
    }

    v4f acc0 = {0.f, 0.f, 0.f, 0.f};   // O tile, dims 0..15
    v4f acc1 = {0.f, 0.f, 0.f, 0.f};   // O tile, dims 16..31
    float den[4] = {0.f, 0.f, 0.f, 0.f};

    const int kbase = w * KEYS_PER_WAVE;

    v8bf cur[8];
    load_chunk(rows, cols, kbase, l16, quad, cur);

    for (int c = 0; c < NCHUNK; ++c) {
        const int kc = kbase + c * CHUNK;

        // --- prefetch chunk c+1 (wraps to 0 on last iter; harmless reload) ---
        const int cn = (c + 1 < NCHUNK) ? (c + 1) : 0;
        v8bf nxt[8];
        load_chunk(rows, cols, kbase + cn * CHUNK, l16, quad, nxt);

        // --- GEMM1: S[q][k] = scale * q.k  (4 key sub-tiles of 16) ---
        v4f s[4];
#pragma unroll
        for (int t = 0; t < 4; ++t)
            s[t] = __builtin_amdgcn_mfma_f32_16x16x32_bf16(afrag, cur[t],
                                                           (v4f){0.f, 0.f, 0.f, 0.f}, 0, 0, 0);

        // --- exp2, den accumulate, stage P in A-operand layout ---
        // C-layout: value (t,r) is (query=quad*4+r, key=t*16+l16)
#pragma unroll
        for (int t = 0; t < 4; ++t) {
#pragma unroll
            for (int r = 0; r < 4; ++r) {
                float wv = __builtin_amdgcn_exp2f(s[t][r]);
                den[r] += wv;
                p_lds[(quad * 4 + r) * PSTRIDE + t * 16 + l16] = (bf16_t)wv;
            }
        }
        // No barrier: slab is per-wave; same-wave DS ops are in-order.

        // --- GEMM2: O[q][d] += P[q][k] * V[k][d], two K=32 steps ---
        v8bf a2_0 = *(const v8bf*)&p_lds[l16 * PSTRIDE + quad * 8];
        v8bf a2_1 = *(const v8bf*)&p_lds[l16 * PSTRIDE + 32 + quad * 8];
        acc0 = __builtin_amdgcn_mfma_f32_16x16x32_bf16(a2_0, cur[4], acc0, 0, 0, 0);
        acc1 = __builtin_amdgcn_mfma_f32_16x16x32_bf16(a2_0, cur[5], acc1, 0, 0, 0);
        acc0 = __builtin_amdgcn_mfma_f32_16x16x32_bf16(a2_1, cur[6], acc0, 0, 0, 0);
        acc1 = __builtin_amdgcn_mfma_f32_16x16x32_bf16(a2_1, cur[7], acc1, 0, 0, 0);

        // rotate register double-buffer
#pragma unroll
        for (int i = 0; i < 8; ++i) cur[i] = nxt[i];
    }

    // --- per-wave partials into own slab (reuse of P region; same wave) ---
    float* rnw = (float*)slab[w];
    float* rdw = (float*)(slab[w] + 2112);
#pragma unroll
    for (int m = 1; m < 16; m <<= 1) {
#pragma unroll
        for (int r = 0; r < 4; ++r) den[r] += __shfl_xor(den[r], m);
    }
#pragma unroll
    for (int r = 0; r < 4; ++r) {
        rnw[(quad * 4 + r) * 33 + l16]      = acc0[r];
        rnw[(quad * 4 + r) * 33 + 16 + l16] = acc1[r];
    }
    if (l16 == 0) {
#pragma unroll
        for (int r = 0; r < 4; ++r) rdw[quad * 4 + r] = den[r];
    }
    __syncthreads();

    // --- epilogue: 512 outputs, 1 per thread; also re-pack for next iter ---
    {
        int q  = tid >> 5;
        int d  = tid & 31;
        float num = 0.f, dn = 0.f;
#pragma unroll
        for (int ww = 0; ww < NWAVE; ++ww) {
            num += ((const float*)slab[ww])[q * 33 + d];
            dn  += ((const float*)(slab[ww] + 2112))[q];
        }
        int gq = q0 + q;
        float xo = Xcur[d * NPT + gq];
        float xn = ETA * num / dn + (1.0f - ETA) * xo;
        Xnext[d * NPT + gq] = xn;
        rows_out[(size_t)gq * DIM + d] = (bf16_t)xn;
        cols_out[(size_t)d * NPT + gq] = (bf16_t)xn;
    }
}

extern "C" void kernel_launch(void* const* d_in, const int* in_sizes, int n_in,
                              void* d_out, int out_size, void* d_ws, size_t ws_size,
                              hipStream_t stream) {
    const float* x_in = (const float*)d_in[0];
    float* out = (float*)d_out;

    // Double-buffered bf16 packs (attn i reads buf[i&1], writes buf[(i+1)&1]).
    const size_t DN = (size_t)DIM * NPT;
    bf16_t* rows0 = (bf16_t*)d_ws;
    bf16_t* cols0 = rows0 + DN;
    bf16_t* rows1 = cols0 + DN;
    bf16_t* cols1 = rows1 + DN;

    const int pack_blocks = (DIM * NPT + 255) / 256; // 1152
    pack_kernel<<<pack_blocks, 256, 0, stream>>>(x_in, rows0, cols0, out);

    for (int it = 0; it < NITER; ++it) {
        const float* Xcur = (it == 0) ? x_in : out + (size_t)it * DN;
        bf16_t* rin  = (it & 1) ? rows1 : rows0;
        bf16_t* cin  = (it & 1) ? cols1 : cols0;
        bf16_t* rout = (it & 1) ? rows0 : rows1;
        bf16_t* cout = (it & 1) ? cols0 : cols1;
        msattn_kernel<<<NPT / 16, 512, 0, stream>>>(Xcur, rin, cin,
                                                    out + (size_t)(it + 1) * DN,
                                                    rout, cout);
    }
}

// Round 4
// 137.304 us; speedup vs baseline: 2.0760x; 2.0551x over previous
//
#include <hip/hip_runtime.h>
#include <hip/hip_bf16.h>

// Mean-shift: 3 iterations of X <- eta * X @ (K/deg) + (1-eta) * X,
// K = exp(2 * X^T X), D=32, N=9216. Fused attention formulation.
// R4: R1-R3 were stuck at 81.5us independent of occupancy/ILP -> per-CU L2
// read-throughput wall (every wave privately streamed 663 MB/iter from L2).
// Redesign: 128 queries/block, 8 waves share double-buffered LDS key tiles
// (85 MB/iter, 7.8x less L2 traffic). Tiles stored in MFMA read order
// (lane i reads base+i*16: conflict-free, no padding). Key-interleaved
// column permutation (subtile t <-> key 4n+t) packs P-stores into
// ds_write_b64; position<->key map is identity so GEMM2 is unchanged.
// Keys split 7 ways across blocks (grid 504 ~= 1.97 blocks/CU); fp32
// partials + small transpose-reduce kernel (fused epilogue + bf16 repack).

#define DIM 32
#define RESO 96
#define NPT (RESO * RESO)          // 9216
#define NITER 3
#define ETA 0.5f
#define SCALE 2.88539008f          // BW * log2(e) = 2 * 1.4426950408

#define QB 128                     // queries per block (8 waves x 16)
#define NQB (NPT / QB)             // 72
#define KSEG 7                     // key segments (grid.y)
#define NCHUNK_TOT (NPT / 64)      // 144 chunks of 64 keys
#define PSTRIDE 72                 // P-slab row stride in elems (144 B, 16B-aligned)

typedef __bf16 bf16_t;
typedef __bf16 v8bf __attribute__((ext_vector_type(8)));
typedef float  v4f  __attribute__((ext_vector_type(4)));

// One-time pack of fp32 X (DIM x NPT) into bf16 row-major (NPT x DIM) and
// bf16 col-major (DIM x NPT); also copies X into d_out slice 0.
__global__ void pack_kernel(const float* __restrict__ X,
                            bf16_t* __restrict__ rows,
                            bf16_t* __restrict__ cols,
                            float* __restrict__ out_copy) {
    int idx = blockIdx.x * 256 + threadIdx.x;
    if (idx >= DIM * NPT) return;
    int d = idx / NPT;
    int n = idx - d * NPT;
    float v = X[idx];
    cols[idx] = (bf16_t)v;
    rows[n * DIM + d] = (bf16_t)v;
    out_copy[idx] = v;
}

// Fused mean-shift partial kernel. Block = 512 thr = 8 waves; wave w owns
// queries [qb*128 + w*16, +16). All waves consume the same 64-key chunk from
// shared LDS tiles (double-buffered, one barrier per chunk). Block covers key
// segment ks; writes fp32 num/den partials.
__global__ __launch_bounds__(512, 4)
void msattn_kernel(const float* __restrict__ Xcur,
                   const bf16_t* __restrict__ rows,
                   const bf16_t* __restrict__ cols,
                   float* __restrict__ part_num,
                   float* __restrict__ part_den) {
    // tiles[buf]: [0..2047] = tileA (GEMM1 B, read-order layout; subtile t at
    // t*512 elems, lane offset lane*8): element = key kc+4*l16+t, dims quad*8..
    // [2048..4095] = tileB (GEMM2 B; frag r=(h,g) at 2048+r*512): element =
    // V^T[dim h*16+l16][keys kc+g*32+quad*8..]. Lane i reads base+i*16B: no
    // bank conflicts by construction.
    __shared__ __align__(16) bf16_t tiles[2][4096];
    __shared__ __align__(16) bf16_t pslab[8][16 * PSTRIDE];

    const int tid  = threadIdx.x;
    const int w    = tid >> 6;
    const int lane = tid & 63;
    const int quad = lane >> 4;
    const int l16  = lane & 15;
    const int qb   = blockIdx.x;
    const int ks   = blockIdx.y;
    const int c0   = (NCHUNK_TOT * ks) / KSEG;
    const int c1   = (NCHUNK_TOT * (ks + 1)) / KSEG;
    const int q0w  = qb * QB + w * 16;

    bf16_t* p_lds = pslab[w];

    // A-frag: A[m=l16 (query)][k=quad*8+j (dim)], BW*log2e folded in.
    v8bf afrag;
#pragma unroll
    for (int j = 0; j < 8; ++j) {
        float v = Xcur[(quad * 8 + j) * NPT + q0w + l16];
        afrag[j] = (bf16_t)(v * SCALE);
    }

    // Per-wave staging source (each wave stages one 1KB piece per chunk).
    const bf16_t* gsrc;
    int gdelta;
    if (w < 4) {           // tileA subtile t=w: key kc+4*l16+w, dims quad*8..
        gsrc = rows + ((size_t)c0 * 64 + 4 * l16 + w) * DIM + quad * 8;
        gdelta = 64 * DIM;
    } else {               // tileB frag r=w-4=(h<<1|g): dim h*16+l16, keys kc+g*32+quad*8..
        int r = w - 4, h = r >> 1, g = r & 1;
        gsrc = cols + (size_t)(h * 16 + l16) * NPT + c0 * 64 + g * 32 + quad * 8;
        gdelta = 64;
    }
    const int ldst = w * 512 + lane * 8;   // elems: dest = read-order slot

    v4f acc0 = {0.f, 0.f, 0.f, 0.f};       // O partial, dims 0..15
    v4f acc1 = {0.f, 0.f, 0.f, 0.f};       // O partial, dims 16..31
    float den[4] = {0.f, 0.f, 0.f, 0.f};

    // Prologue: stage first chunk into buffer 0.
    {
        v8bf st = *(const v8bf*)gsrc;
        gsrc += gdelta;
        *(v8bf*)&tiles[0][ldst] = st;
    }
    __syncthreads();

    for (int c = c0; c < c1; ++c) {
        const int cc = c - c0;
        const bf16_t* tb = tiles[cc & 1];
        const bool more = (c + 1 < c1);

        // Prefetch next chunk's staging piece into registers (global in
        // flight across this chunk's compute).
        v8bf stn;
        if (more) { stn = *(const v8bf*)gsrc; gsrc += gdelta; }

        // --- GEMM1: S subtile t, column n=l16 <-> key kc+4*n+t ---
        v4f s[4];
#pragma unroll
        for (int t = 0; t < 4; ++t) {
            v8bf b = *(const v8bf*)&tb[t * 512 + lane * 8];
            s[t] = __builtin_amdgcn_mfma_f32_16x16x32_bf16(afrag, b,
                                                           (v4f){0.f, 0.f, 0.f, 0.f}, 0, 0, 0);
        }

        // --- exp2 + pack 4 bf16 -> one b64 store per r ---
        // C-layout: (q=quad*4+r, col l16) = S[q][key kc+4*l16+t]; store at
        // P position 4*l16+t (position p <-> key kc+p: identity).
#pragma unroll
        for (int r = 0; r < 4; ++r) {
            union { bf16_t h[4]; unsigned long long u; } pk;
#pragma unroll
            for (int t = 0; t < 4; ++t) {
                float wv = __builtin_amdgcn_exp2f(s[t][r]);
                den[r] += wv;
                pk.h[t] = (bf16_t)wv;
            }
            *(unsigned long long*)&p_lds[(quad * 4 + r) * PSTRIDE + 4 * l16] = pk.u;
        }

        // --- GEMM2: O[q][d] += P[q][k] V[k][d] (wave-local LDS, in-order) ---
        v8bf a20 = *(const v8bf*)&p_lds[l16 * PSTRIDE + quad * 8];        // positions 0..31
        v8bf a21 = *(const v8bf*)&p_lds[l16 * PSTRIDE + 32 + quad * 8];   // positions 32..63
        v8bf b00 = *(const v8bf*)&tb[2048 + 0 * 512 + lane * 8];  // h0,g0
        v8bf b01 = *(const v8bf*)&tb[2048 + 1 * 512 + lane * 8];  // h0,g1
        v8bf b10 = *(const v8bf*)&tb[2048 + 2 * 512 + lane * 8];  // h1,g0
        v8bf b11 = *(const v8bf*)&tb[2048 + 3 * 512 + lane * 8];  // h1,g1
        acc0 = __builtin_amdgcn_mfma_f32_16x16x32_bf16(a20, b00, acc0, 0, 0, 0);
        acc1 = __builtin_amdgcn_mfma_f32_16x16x32_bf16(a20, b10, acc1, 0, 0, 0);
        acc0 = __builtin_amdgcn_mfma_f32_16x16x32_bf16(a21, b01, acc0, 0, 0, 0);
        acc1 = __builtin_amdgcn_mfma_f32_16x16x32_bf16(a21, b11, acc1, 0, 0, 0);

        // Write staged piece for chunk c+1, then one barrier.
        if (more) *(v8bf*)&tiles[(cc + 1) & 1][ldst] = stn;
        __syncthreads();
    }

    // --- epilogue: each wave owns its 16 queries outright (no cross-wave
    // reduction). den: reduce across the 16 lanes of each quad. ---
#pragma unroll
    for (int m = 1; m < 16; m <<= 1) {
#pragma unroll
        for (int r = 0; r < 4; ++r) den[r] += __shfl_xor(den[r], m);
    }
    float* pn = part_num + (size_t)ks * NPT * DIM;
#pragma unroll
    for (int r = 0; r < 4; ++r) {
        int gq = q0w + quad * 4 + r;
        pn[(size_t)gq * DIM + l16]      = acc0[r];
        pn[(size_t)gq * DIM + 16 + l16] = acc1[r];
    }
    if (l16 == 0) {
#pragma unroll
        for (int r = 0; r < 4; ++r)
            part_den[ks * NPT + q0w + quad * 4 + r] = den[r];
    }
}

// Reduce KSEG partials, apply eta-step, write Xnext + next iteration's bf16
// rows/cols. Tiled 32q x 32d with LDS transpose so every global access is
// coalesced. Grid = NPT/32 = 288 blocks x 256 threads.
__global__ __launch_bounds__(256, 4)
void reduce_kernel(const float* __restrict__ part_num,
                   const float* __restrict__ part_den,
                   const float* __restrict__ Xcur,
                   float* __restrict__ Xnext,
                   bf16_t* __restrict__ rows_out,
                   bf16_t* __restrict__ cols_out) {
    __shared__ float tnum[32][33];
    __shared__ float txn[32][33];
    __shared__ float tden[32];

    const int tid = threadIdx.x;
    const int q0  = blockIdx.x * 32;

    // pass 1 (q-major, coalesced partial reads)
#pragma unroll
    for (int j = 0; j < 4; ++j) {
        int idx = tid + j * 256;
        int qq = idx >> 5, d = idx & 31;
        float s = 0.f;
#pragma unroll
        for (int ss = 0; ss < KSEG; ++ss)
            s += part_num[((size_t)ss * NPT + q0 + qq) * DIM + d];
        tnum[qq][d] = s;
    }
    if (tid < 32) {
        float s = 0.f;
#pragma unroll
        for (int ss = 0; ss < KSEG; ++ss)
            s += part_den[ss * NPT + q0 + tid];
        tden[tid] = s;
    }
    __syncthreads();

    // pass 2 (d-major: Xcur read, Xnext + cols_out writes coalesced)
#pragma unroll
    for (int j = 0; j < 4; ++j) {
        int idx = tid + j * 256;
        int d = idx >> 5, qq = idx & 31;
        float num = tnum[qq][d];
        float dn  = tden[qq];
        float xo  = Xcur[d * NPT + q0 + qq];
        float xn  = ETA * num / dn + (1.0f - ETA) * xo;
        Xnext[d * NPT + q0 + qq] = xn;
        cols_out[(size_t)d * NPT + q0 + qq] = (bf16_t)xn;
        txn[qq][d] = xn;
    }
    __syncthreads();

    // pass 3 (q-major: rows_out coalesced)
#pragma unroll
    for (int j = 0; j < 4; ++j) {
        int idx = tid + j * 256;
        int qq = idx >> 5, d = idx & 31;
        rows_out[(size_t)(q0 + qq) * DIM + d] = (bf16_t)txn[qq][d];
    }
}

extern "C" void kernel_launch(void* const* d_in, const int* in_sizes, int n_in,
                              void* d_out, int out_size, void* d_ws, size_t ws_size,
                              hipStream_t stream) {
    const float* x_in = (const float*)d_in[0];
    float* out = (float*)d_out;

    const size_t DN = (size_t)DIM * NPT;
    // Workspace: 4 bf16 pack buffers (ping-pong), fp32 partials.
    bf16_t* rows0 = (bf16_t*)d_ws;
    bf16_t* cols0 = rows0 + DN;
    bf16_t* rows1 = cols0 + DN;
    bf16_t* cols1 = rows1 + DN;
    float* part_num = (float*)(cols1 + DN);            // KSEG * NPT * DIM f32
    float* part_den = part_num + (size_t)KSEG * NPT * DIM;  // KSEG * NPT f32

    const int pack_blocks = (DIM * NPT + 255) / 256;   // 1152
    pack_kernel<<<pack_blocks, 256, 0, stream>>>(x_in, rows0, cols0, out);

    for (int it = 0; it < NITER; ++it) {
        const float* Xcur = (it == 0) ? x_in : out + (size_t)it * DN;
        bf16_t* rin  = (it & 1) ? rows1 : rows0;
        bf16_t* cin  = (it & 1) ? cols1 : cols0;
        bf16_t* rout = (it & 1) ? rows0 : rows1;
        bf16_t* cout = (it & 1) ? cols0 : cols1;
        msattn_kernel<<<dim3(NQB, KSEG), 512, 0, stream>>>(Xcur, rin, cin,
                                                           part_num, part_den);
        reduce_kernel<<<NPT / 32, 256, 0, stream>>>(part_num, part_den, Xcur,
                                                    out + (size_t)(it + 1) * DN,
                                                    rout, cout);
    }
}